// Round 21
// baseline (133.565 us; speedup 1.0000x reference)
//
#include <hip/hip_runtime.h>
#include <hip/hip_bf16.h>

typedef unsigned short u16;
typedef unsigned int u32;
typedef __attribute__((ext_vector_type(8))) short short8;
typedef __attribute__((ext_vector_type(4))) float f32x4;
typedef __attribute__((ext_vector_type(16))) float f32x16;
typedef __attribute__((ext_vector_type(4))) unsigned int uint4v;

#define VMW(n) asm volatile("s_waitcnt vmcnt(" #n ")" ::: "memory")
#define BARRIER() do { asm volatile("" ::: "memory"); __builtin_amdgcn_s_barrier(); asm volatile("" ::: "memory"); } while (0)

__device__ __forceinline__ u16 f2bf(float f) {
    union { float f; unsigned int u; } v; v.f = f;
    unsigned int u = v.u;
    return (u16)((u + 0x7FFFu + ((u >> 16) & 1u)) >> 16);
}
__device__ __forceinline__ u32 pk2(float a, float b) {
    return ((u32)f2bf(b) << 16) | (u32)f2bf(a);
}
__device__ __forceinline__ void gload_lds16(const u16* g, u16* l) {
    __builtin_amdgcn_global_load_lds((const __attribute__((address_space(1))) void*)g,
                                     (__attribute__((address_space(3))) void*)l, 16, 0, 0);
}

// ---------------- fused prep (r20-exact): x->bf16 + both weight transposes ----------------
__global__ __launch_bounds__(256) void k_prep(
    const float* __restrict__ x, u16* __restrict__ xb,
    const float* __restrict__ W_qkv, u16* __restrict__ wqt,
    const float* __restrict__ W_out, u16* __restrict__ wot)
{
    __shared__ u16 t[32][33];
    int bid = blockIdx.x, tid = threadIdx.x;
    if (bid < 6144) {
        int i = bid * 256 + tid;
        float4 v = ((const float4*)x)[i];
        ushort4 r;
        r.x = f2bf(v.x); r.y = f2bf(v.y); r.z = f2bf(v.z); r.w = f2bf(v.w);
        ((ushort4*)xb)[i] = r;
        return;
    }
    const float* W; u16* Wt; int K, N, n0, k0;
    if (bid < 7872) {
        int q = bid - 6144;
        W = W_qkv; Wt = wqt; K = 768; N = 2304;
        n0 = (q % 72) * 32; k0 = (q / 72) * 32;
    } else {
        int q = bid - 7872;
        W = W_out; Wt = wot; K = 768; N = 768;
        n0 = (q % 24) * 32; k0 = (q / 24) * 32;
    }
    int tx = tid & 31, ty = tid >> 5;
    #pragma unroll
    for (int i = 0; i < 4; i++) {
        t[ty + i * 8][tx] = f2bf(W[(long)(k0 + ty + i * 8) * N + n0 + tx]);
    }
    __syncthreads();
    #pragma unroll
    for (int i = 0; i < 4; i++) {
        Wt[(long)(n0 + ty + i * 8) * K + k0 + tx] = t[tx][ty + i * 8];
    }
}

// ---------------- prep: qkv V-columns -> Vt [BH][64][1024] (r15-exact) ----------------
__global__ void k_vt(const u16* __restrict__ qkv, u16* __restrict__ vt) {
    __shared__ u16 s[32][33];
    int t0 = blockIdx.x * 32, d0 = blockIdx.y * 32, bh = blockIdx.z;
    int b = bh / 12, h = bh - b * 12;
    int tx = threadIdx.x, ty = threadIdx.y;
    const u16* src = qkv + (size_t)(b * 1024 + t0) * 2304 + 1536 + h * 64 + d0;
    #pragma unroll
    for (int i = 0; i < 4; i++) {
        s[ty + i * 8][tx] = src[(size_t)(ty + i * 8) * 2304 + tx];
    }
    __syncthreads();
    u16* dst = vt + (size_t)bh * 65536 + (size_t)d0 * 1024 + t0;
    #pragma unroll
    for (int i = 0; i < 4; i++) {
        dst[(size_t)(ty + i * 8) * 1024 + tx] = s[tx][ty + i * 8];
    }
}

// ---------------- QKV GEMM (r17-exact): ring-3 gload_lds, counted vmcnt, 128x128 ----
__global__ __launch_bounds__(256) void k_gemm_qkv(
    const u16* __restrict__ A, const u16* __restrict__ Bt, const float* __restrict__ bias,
    u16* __restrict__ Cb, int M, int N, int K)
{
    __shared__ u16 lA[3][128][32];
    __shared__ u16 lB[3][128][32];
    int tid = threadIdx.x;
    int wid = tid >> 6, lane = tid & 63;
    int wm = wid >> 1, wn = wid & 1;
    int ln = lane & 15, gp = lane >> 4;
    int gm0 = blockIdx.x * 128, gn0 = blockIdx.y * 128;

    f32x4 zf = {0.f, 0.f, 0.f, 0.f};
    f32x4 acc[4][4];
    #pragma unroll
    for (int i = 0; i < 4; i++)
        #pragma unroll
        for (int j = 0; j < 4; j++) acc[i][j] = zf;

    int srow = wid * 32 + (lane >> 2);
    int scol = (((lane & 3) ^ ((lane >> 3) & 3))) * 8;
    const u16* gA0 = &A [(size_t)(gm0 + srow) * K + scol];
    const u16* gA1 = gA0 + (size_t)16 * K;
    const u16* gB0 = &Bt[(size_t)(gn0 + srow) * K + scol];
    const u16* gB1 = gB0 + (size_t)16 * K;

    int rc = (gp ^ ((ln >> 1) & 3)) * 8;

    auto stage = [&](int k0, int bb) {
        gload_lds16(gA0 + k0, &lA[bb][wid * 32][0]);
        gload_lds16(gA1 + k0, &lA[bb][wid * 32 + 16][0]);
        gload_lds16(gB0 + k0, &lB[bb][wid * 32][0]);
        gload_lds16(gB1 + k0, &lB[bb][wid * 32 + 16][0]);
    };
    auto compute = [&](int bb) {
        short8 af[4], bfr[4];
        #pragma unroll
        for (int i = 0; i < 4; i++) {
            af[i]  = *(const short8*)&lA[bb][wm * 64 + i * 16 + ln][rc];
            bfr[i] = *(const short8*)&lB[bb][wn * 64 + i * 16 + ln][rc];
        }
        __builtin_amdgcn_s_setprio(1);
        #pragma unroll
        for (int i = 0; i < 4; i++)
            #pragma unroll
            for (int j = 0; j < 4; j++)
                acc[i][j] = __builtin_amdgcn_mfma_f32_16x16x32_bf16(af[i], bfr[j], acc[i][j], 0, 0, 0);
        __builtin_amdgcn_s_setprio(0);
    };

    int nk = K >> 5;                  // 24 for K=768; nk % 3 == 0
    stage(0, 0);
    stage(32, 1);
    stage(64, 2);
    VMW(8);
    BARRIER();
    #pragma unroll 3
    for (int t = 0; t < nk; ++t) {
        int c = t % 3;
        compute(c);
        BARRIER();
        if (t + 3 < nk) {
            stage((t + 3) << 5, c);
            VMW(8);
        } else if (t + 2 < nk) {
            VMW(4);
        } else {
            VMW(0);
        }
        BARRIER();
    }

    #pragma unroll
    for (int i = 0; i < 4; i++) {
        #pragma unroll
        for (int j = 0; j < 4; j++) {
            #pragma unroll
            for (int r = 0; r < 4; r++) {
                int m = gm0 + wm * 64 + i * 16 + gp * 4 + r;
                int n = gn0 + wn * 64 + j * 16 + ln;
                Cb[(long)m * N + n] = f2bf(acc[i][j][r] + bias[n]);
            }
        }
    }
}

// ---------------- out-proj GEMM (r15-exact): 128x128, padded reg-staged ----------------
__global__ __launch_bounds__(256) void k_gemm_small(
    const u16* __restrict__ A, const u16* __restrict__ Bt, const float* __restrict__ bias,
    float* __restrict__ Cf, int M, int N, int K)
{
    __shared__ u16 lA[128][40];   // +8 pad: 2-way alias (benign, m136)
    __shared__ u16 lB[128][40];
    int tid = threadIdx.x;
    int wid = tid >> 6, lane = tid & 63;
    int wm = wid >> 1, wn = wid & 1;
    int ln = lane & 15, gp = lane >> 4;
    int gm0 = blockIdx.x * 128, gn0 = blockIdx.y * 128;

    f32x4 zf = {0.f, 0.f, 0.f, 0.f};
    f32x4 acc[4][4];
    #pragma unroll
    for (int i = 0; i < 4; i++)
        #pragma unroll
        for (int j = 0; j < 4; j++) acc[i][j] = zf;

    int sr = tid >> 2;
    int sc = (tid & 3) * 8;

    for (int k0 = 0; k0 < K; k0 += 32) {
        #pragma unroll
        for (int j = 0; j < 2; j++) {
            int r = sr + j * 64;
            *(uint4v*)&lA[r][sc] = *(const uint4v*)&A[(long)(gm0 + r) * K + k0 + sc];
            *(uint4v*)&lB[r][sc] = *(const uint4v*)&Bt[(long)(gn0 + r) * K + k0 + sc];
        }
        __syncthreads();
        short8 af[4], bfr[4];
        #pragma unroll
        for (int i = 0; i < 4; i++) {
            af[i]  = *(const short8*)&lA[wm * 64 + i * 16 + ln][gp * 8];
            bfr[i] = *(const short8*)&lB[wn * 64 + i * 16 + ln][gp * 8];
        }
        #pragma unroll
        for (int i = 0; i < 4; i++)
            #pragma unroll
            for (int j = 0; j < 4; j++)
                acc[i][j] = __builtin_amdgcn_mfma_f32_16x16x32_bf16(af[i], bfr[j], acc[i][j], 0, 0, 0);
        __syncthreads();
    }

    #pragma unroll
    for (int i = 0; i < 4; i++) {
        #pragma unroll
        for (int j = 0; j < 4; j++) {
            #pragma unroll
            for (int r = 0; r < 4; r++) {
                int m = gm0 + wm * 64 + i * 16 + gp * 4 + r;
                int n = gn0 + wn * 64 + j * 16 + ln;
                Cf[(long)m * N + n] = acc[i][j][r] + bias[n];
            }
        }
    }
}

// ---------------- causal flash attention v4 (r15-exact): LDS-staged K/V, 1 wave/block ----
__global__ __launch_bounds__(64, 3) void k_attn(
    const u16* __restrict__ qkv, const u16* __restrict__ Vt,
    u16* __restrict__ O)
{
    __shared__ u16 sK[2048];   // [32 k-rows][64] ; chunk c stored at c^(r&7)
    __shared__ u16 sV[2048];   // [64 d-rows][32] ; chunk c stored at c^(r&3)^((r>>2)&3)
    int lane = threadIdx.x;
    int l31 = lane & 31, hi = lane >> 5;
    int bx = blockIdx.x;
    int qtq = bx / 96, bh = bx - qtq * 96;
    int qt = 31 - qtq, q0 = qt * 32;            // heavy blocks first
    int b = bh / 12, h = bh - b * 12;
    const u16* Qb  = qkv + (size_t)(b * 1024) * 2304 + h * 64;
    const u16* Kbb = Qb + 768;
    const u16* Vb  = Vt + (size_t)bh * 65536;

    short8 qf[4];
    #pragma unroll
    for (int ch = 0; ch < 4; ch++)
        qf[ch] = *(const short8*)&Qb[(size_t)(q0 + l31) * 2304 + ch * 16 + hi * 8];

    int rK = lane >> 3, cK = lane & 7;
    int rV = lane >> 2, cV = lane & 3;

    uint4v rk[4], rv[4];
    auto gload = [&](int kt) {
        #pragma unroll
        for (int j = 0; j < 4; j++) {
            int r = j * 8 + rK;
            rk[j] = *(const uint4v*)&Kbb[(size_t)(kt + r) * 2304 + cK * 8];
        }
        #pragma unroll
        for (int j = 0; j < 4; j++) {
            int r = j * 16 + rV;
            rv[j] = *(const uint4v*)&Vb[(size_t)r * 1024 + kt + cV * 8];
        }
    };
    auto swrite = [&]() {
        #pragma unroll
        for (int j = 0; j < 4; j++) {
            int r = j * 8 + rK;
            *(uint4v*)&sK[r * 64 + ((cK ^ (r & 7)) * 8)] = rk[j];
        }
        #pragma unroll
        for (int j = 0; j < 4; j++) {
            int r = j * 16 + rV;
            *(uint4v*)&sV[r * 32 + ((cV ^ (r & 3) ^ ((r >> 2) & 3)) * 8)] = rv[j];
        }
    };

    f32x16 o0 = {}, o1 = {};
    float mrun = -INFINITY, lsum = 0.f;
    const float SC = 0.18033688011f;            // 0.125 * log2(e)
    int swl = l31 & 7;
    int swv = (l31 & 3) ^ ((l31 >> 2) & 3);

    int nit = qt + 1;
    gload(0);
    swrite();
    for (int it = 0; it < nit; it++) {
        int kt = it * 32;
        if (it + 1 < nit) gload(kt + 32);
        f32x16 sa = {}, sb = {};
        {
            short8 kf0 = *(const short8*)&sK[l31 * 64 + (((0 + hi) ^ swl) * 8)];
            short8 kf1 = *(const short8*)&sK[l31 * 64 + (((2 + hi) ^ swl) * 8)];
            short8 kf2 = *(const short8*)&sK[l31 * 64 + (((4 + hi) ^ swl) * 8)];
            short8 kf3 = *(const short8*)&sK[l31 * 64 + (((6 + hi) ^ swl) * 8)];
            sa = __builtin_amdgcn_mfma_f32_32x32x16_bf16(kf0, qf[0], sa, 0, 0, 0);
            sb = __builtin_amdgcn_mfma_f32_32x32x16_bf16(kf2, qf[2], sb, 0, 0, 0);
            sa = __builtin_amdgcn_mfma_f32_32x32x16_bf16(kf1, qf[1], sa, 0, 0, 0);
            sb = __builtin_amdgcn_mfma_f32_32x32x16_bf16(kf3, qf[3], sb, 0, 0, 0);
        }
        float raw[16];
        #pragma unroll
        for (int r = 0; r < 16; r++) raw[r] = sa[r] + sb[r];
        if (it == nit - 1) {
            #pragma unroll
            for (int r = 0; r < 16; r++) {
                int crow = (r & 3) + 8 * (r >> 2) + 4 * hi;
                raw[r] = (crow <= l31) ? raw[r] : -1e30f;
            }
        }
        float t8[8];
        #pragma unroll
        for (int i = 0; i < 8; i++) t8[i] = fmaxf(raw[i], raw[i + 8]);
        float t4a = fmaxf(t8[0], t8[1]), t4b = fmaxf(t8[2], t8[3]);
        float t4c = fmaxf(t8[4], t8[5]), t4d = fmaxf(t8[6], t8[7]);
        float tm = fmaxf(fmaxf(t4a, t4b), fmaxf(t4c, t4d));
        tm = fmaxf(tm, __shfl_xor(tm, 32));
        float stm = tm * SC;
        if (!__all(stm - mrun <= 8.0f)) {       // defer-max (T13, THR=8)
            float mn = fmaxf(mrun, stm);
            float scale = exp2f(mrun - mn);
            lsum *= scale;
            #pragma unroll
            for (int r = 0; r < 16; r++) { o0[r] *= scale; o1[r] *= scale; }
            mrun = mn;
        }
        float ps[16];
        float rs = 0.f;
        #pragma unroll
        for (int r = 0; r < 16; r++) {
            ps[r] = exp2f(fmaf(raw[r], SC, -mrun));
            rs += ps[r];
        }
        rs += __shfl_xor(rs, 32);
        lsum += rs;
        u32 c[8], sw[8];
        #pragma unroll
        for (int i = 0; i < 8; i++) c[i] = pk2(ps[2 * i], ps[2 * i + 1]);
        #pragma unroll
        for (int i = 0; i < 8; i++) sw[i] = (u32)__shfl_xor((int)c[i], 32);
        union { u32 u[4]; short8 s8; } pb0, pb1;
        pb0.u[0] = hi ? sw[2] : c[0];
        pb0.u[1] = hi ? sw[3] : c[1];
        pb0.u[2] = hi ? c[2]  : sw[0];
        pb0.u[3] = hi ? c[3]  : sw[1];
        pb1.u[0] = hi ? sw[6] : c[4];
        pb1.u[1] = hi ? sw[7] : c[5];
        pb1.u[2] = hi ? c[6]  : sw[4];
        pb1.u[3] = hi ? c[7]  : sw[5];
        #pragma unroll
        for (int kh = 0; kh < 2; kh++) {
            const short8* pbp = kh ? &pb1.s8 : &pb0.s8;
            int p = (((kh * 2 + hi) ^ swv) * 8);
            short8 vf0 = *(const short8*)&sV[l31 * 32 + p];
            short8 vf1 = *(const short8*)&sV[(32 + l31) * 32 + p];
            o0 = __builtin_amdgcn_mfma_f32_32x32x16_bf16(vf0, *pbp, o0, 0, 0, 0);
            o1 = __builtin_amdgcn_mfma_f32_32x32x16_bf16(vf1, *pbp, o1, 0, 0, 0);
        }
        if (it + 1 < nit) swrite();
    }

    float inv = 1.0f / lsum;
    int t = q0 + l31;
    size_t base = ((size_t)(b * 1024 + t)) * 768 + h * 64;
    #pragma unroll
    for (int rq = 0; rq < 4; rq++) {
        ushort4 u0, u1;
        u0.x = f2bf(o0[4 * rq + 0] * inv); u0.y = f2bf(o0[4 * rq + 1] * inv);
        u0.z = f2bf(o0[4 * rq + 2] * inv); u0.w = f2bf(o0[4 * rq + 3] * inv);
        u1.x = f2bf(o1[4 * rq + 0] * inv); u1.y = f2bf(o1[4 * rq + 1] * inv);
        u1.z = f2bf(o1[4 * rq + 2] * inv); u1.w = f2bf(o1[4 * rq + 3] * inv);
        *(ushort4*)&O[base + rq * 8 + hi * 4]      = u0;
        *(ushort4*)&O[base + 32 + rq * 8 + hi * 4] = u1;
    }
}

extern "C" void kernel_launch(void* const* d_in, const int* in_sizes, int n_in,
                              void* d_out, int out_size, void* d_ws, size_t ws_size,
                              hipStream_t stream)
{
    const float* x     = (const float*)d_in[0];
    const float* W_qkv = (const float*)d_in[1];
    const float* b_qkv = (const float*)d_in[2];
    const float* W_out = (const float*)d_in[3];
    const float* b_out = (const float*)d_in[4];
    float* out = (float*)d_out;

    char* w = (char*)d_ws;
    u16* xb   = (u16*)w; w += (size_t)8192 * 768 * 2;
    u16* wqt  = (u16*)w; w += (size_t)2304 * 768 * 2;
    u16* wot  = (u16*)w; w += (size_t)768 * 768 * 2;
    u16* qkv  = (u16*)w; w += (size_t)8192 * 2304 * 2;
    u16* vt   = (u16*)w; w += (size_t)96 * 64 * 1024 * 2;
    u16* ao   = (u16*)w; w += (size_t)8192 * 768 * 2;

    k_prep<<<dim3(8448), 256, 0, stream>>>(x, xb, W_qkv, wqt, W_out, wot);
    k_gemm_qkv<<<dim3(64, 18), 256, 0, stream>>>(xb, wqt, b_qkv, qkv, 8192, 2304, 768);
    k_vt<<<dim3(32, 2, 96), dim3(32, 8), 0, stream>>>(qkv, vt);
    k_attn<<<dim3(3072), 64, 0, stream>>>(qkv, vt, ao);
    k_gemm_small<<<dim3(64, 6), 256, 0, stream>>>(ao, wot, b_out, out, 8192, 768, 768);
}

// Round 22
// 131.773 us; speedup vs baseline: 1.0136x; 1.0136x over previous
//
#include <hip/hip_runtime.h>
#include <hip/hip_bf16.h>

typedef unsigned short u16;
typedef unsigned int u32;
typedef __attribute__((ext_vector_type(8))) short short8;
typedef __attribute__((ext_vector_type(4))) float f32x4;
typedef __attribute__((ext_vector_type(16))) float f32x16;
typedef __attribute__((ext_vector_type(4))) unsigned int uint4v;

__device__ __forceinline__ u16 f2bf(float f) {
    union { float f; unsigned int u; } v; v.f = f;
    unsigned int u = v.u;
    return (u16)((u + 0x7FFFu + ((u >> 16) & 1u)) >> 16);
}
__device__ __forceinline__ u32 pk2(float a, float b) {
    return ((u32)f2bf(b) << 16) | (u32)f2bf(a);
}

// ---------------- fused prep (r20-exact): x->bf16 + both weight transposes ----------------
__global__ __launch_bounds__(256) void k_prep(
    const float* __restrict__ x, u16* __restrict__ xb,
    const float* __restrict__ W_qkv, u16* __restrict__ wqt,
    const float* __restrict__ W_out, u16* __restrict__ wot)
{
    __shared__ u16 t[32][33];
    int bid = blockIdx.x, tid = threadIdx.x;
    if (bid < 6144) {
        int i = bid * 256 + tid;
        float4 v = ((const float4*)x)[i];
        ushort4 r;
        r.x = f2bf(v.x); r.y = f2bf(v.y); r.z = f2bf(v.z); r.w = f2bf(v.w);
        ((ushort4*)xb)[i] = r;
        return;
    }
    const float* W; u16* Wt; int K, N, n0, k0;
    if (bid < 7872) {
        int q = bid - 6144;
        W = W_qkv; Wt = wqt; K = 768; N = 2304;
        n0 = (q % 72) * 32; k0 = (q / 72) * 32;
    } else {
        int q = bid - 7872;
        W = W_out; Wt = wot; K = 768; N = 768;
        n0 = (q % 24) * 32; k0 = (q / 24) * 32;
    }
    int tx = tid & 31, ty = tid >> 5;
    #pragma unroll
    for (int i = 0; i < 4; i++) {
        t[ty + i * 8][tx] = f2bf(W[(long)(k0 + ty + i * 8) * N + n0 + tx]);
    }
    __syncthreads();
    #pragma unroll
    for (int i = 0; i < 4; i++) {
        Wt[(long)(n0 + ty + i * 8) * K + k0 + tx] = t[tx][ty + i * 8];
    }
}

// ---------------- prep v2: qkv V-columns -> Vt [BH][64][1024], full-line tiles ----------
// [64 t][64 d] tile: reads are 128B full lines (32 u32/row), writes are 128B
// Vt rows (64 u16). LDS [64][33] u32 pad -> 2-way alias both phases (free).
__global__ __launch_bounds__(256) void k_vt(const u16* __restrict__ qkv, u16* __restrict__ vt) {
    __shared__ u32 s32[64][33];
    int t0 = blockIdx.x * 64, bh = blockIdx.y;
    int b = bh / 12, h = bh - b * 12;
    int tid = threadIdx.x;
    const u16* src = qkv + (size_t)(b * 1024 + t0) * 2304 + 1536 + h * 64;
    int tx = tid & 31, ty = tid >> 5;          // read: 32 u32-cols x 8 t-rows
    #pragma unroll
    for (int i = 0; i < 8; i++) {
        int t = ty + i * 8;
        s32[t][tx] = *(const u32*)&src[(size_t)t * 2304 + tx * 2];
    }
    __syncthreads();
    const u16* s16 = (const u16*)s32;          // row pitch 66 u16
    u16* dst = vt + (size_t)bh * 65536 + t0;
    int tw = tid & 63, dw = tid >> 6;          // write: 64 t x 4 d-rows per iter
    #pragma unroll
    for (int j = 0; j < 16; j++) {
        int d = dw + j * 4;
        dst[(size_t)d * 1024 + tw] = s16[tw * 66 + d];
    }
}

// ---------------- bf16 MFMA GEMM (r20-exact): BK=32, padded LDS, uniform epilogue ----
template<int EPI>
__global__ __launch_bounds__(256) void k_gemm_bt(
    const u16* __restrict__ A, const u16* __restrict__ Bt, const float* __restrict__ bias,
    float* __restrict__ Cf, u16* __restrict__ Cb,
    int M, int N, int K)
{
    __shared__ u16 lA[128][40];   // +8 pad: 2-way alias (benign, m136)
    __shared__ u16 lB[128][40];
    int tid = threadIdx.x;
    int wid = tid >> 6, lane = tid & 63;
    int wm = wid >> 1, wn = wid & 1;
    int ln = lane & 15, gp = lane >> 4;
    int gm0 = blockIdx.x * 128, gn0 = blockIdx.y * 128;

    f32x4 zf = {0.f, 0.f, 0.f, 0.f};
    f32x4 acc[4][4];
    #pragma unroll
    for (int i = 0; i < 4; i++)
        #pragma unroll
        for (int j = 0; j < 4; j++) acc[i][j] = zf;

    int sr = tid >> 2;
    int sc = (tid & 3) * 8;

    for (int k0 = 0; k0 < K; k0 += 32) {
        #pragma unroll
        for (int j = 0; j < 2; j++) {
            int r = sr + j * 64;
            *(uint4v*)&lA[r][sc] = *(const uint4v*)&A[(long)(gm0 + r) * K + k0 + sc];
            *(uint4v*)&lB[r][sc] = *(const uint4v*)&Bt[(long)(gn0 + r) * K + k0 + sc];
        }
        __syncthreads();
        short8 af[4], bfr[4];
        #pragma unroll
        for (int i = 0; i < 4; i++) {
            af[i]  = *(const short8*)&lA[wm * 64 + i * 16 + ln][gp * 8];
            bfr[i] = *(const short8*)&lB[wn * 64 + i * 16 + ln][gp * 8];
        }
        #pragma unroll
        for (int i = 0; i < 4; i++)
            #pragma unroll
            for (int j = 0; j < 4; j++)
                acc[i][j] = __builtin_amdgcn_mfma_f32_16x16x32_bf16(af[i], bfr[j], acc[i][j], 0, 0, 0);
        __syncthreads();
    }

    #pragma unroll
    for (int i = 0; i < 4; i++) {
        #pragma unroll
        for (int j = 0; j < 4; j++) {
            #pragma unroll
            for (int r = 0; r < 4; r++) {
                int m = gm0 + wm * 64 + i * 16 + gp * 4 + r;
                int n = gn0 + wn * 64 + j * 16 + ln;
                float v = acc[i][j][r] + bias[n];
                if (EPI == 0) Cf[(long)m * N + n] = v;
                else          Cb[(long)m * N + n] = f2bf(v);
            }
        }
    }
}

// ---------------- causal flash attention v4 (r20-exact): LDS-staged K/V, 1 wave/block ----
__global__ __launch_bounds__(64, 3) void k_attn(
    const u16* __restrict__ qkv, const u16* __restrict__ Vt,
    u16* __restrict__ O)
{
    __shared__ u16 sK[2048];   // [32 k-rows][64] ; chunk c stored at c^(r&7)
    __shared__ u16 sV[2048];   // [64 d-rows][32] ; chunk c stored at c^(r&3)^((r>>2)&3)
    int lane = threadIdx.x;
    int l31 = lane & 31, hi = lane >> 5;
    int bx = blockIdx.x;
    int qtq = bx / 96, bh = bx - qtq * 96;
    int qt = 31 - qtq, q0 = qt * 32;            // heavy blocks first
    int b = bh / 12, h = bh - b * 12;
    const u16* Qb  = qkv + (size_t)(b * 1024) * 2304 + h * 64;
    const u16* Kbb = Qb + 768;
    const u16* Vb  = Vt + (size_t)bh * 65536;

    short8 qf[4];
    #pragma unroll
    for (int ch = 0; ch < 4; ch++)
        qf[ch] = *(const short8*)&Qb[(size_t)(q0 + l31) * 2304 + ch * 16 + hi * 8];

    int rK = lane >> 3, cK = lane & 7;
    int rV = lane >> 2, cV = lane & 3;

    uint4v rk[4], rv[4];
    auto gload = [&](int kt) {
        #pragma unroll
        for (int j = 0; j < 4; j++) {
            int r = j * 8 + rK;
            rk[j] = *(const uint4v*)&Kbb[(size_t)(kt + r) * 2304 + cK * 8];
        }
        #pragma unroll
        for (int j = 0; j < 4; j++) {
            int r = j * 16 + rV;
            rv[j] = *(const uint4v*)&Vb[(size_t)r * 1024 + kt + cV * 8];
        }
    };
    auto swrite = [&]() {
        #pragma unroll
        for (int j = 0; j < 4; j++) {
            int r = j * 8 + rK;
            *(uint4v*)&sK[r * 64 + ((cK ^ (r & 7)) * 8)] = rk[j];
        }
        #pragma unroll
        for (int j = 0; j < 4; j++) {
            int r = j * 16 + rV;
            *(uint4v*)&sV[r * 32 + ((cV ^ (r & 3) ^ ((r >> 2) & 3)) * 8)] = rv[j];
        }
    };

    f32x16 o0 = {}, o1 = {};
    float mrun = -INFINITY, lsum = 0.f;
    const float SC = 0.18033688011f;            // 0.125 * log2(e)
    int swl = l31 & 7;
    int swv = (l31 & 3) ^ ((l31 >> 2) & 3);

    int nit = qt + 1;
    gload(0);
    swrite();
    for (int it = 0; it < nit; it++) {
        int kt = it * 32;
        if (it + 1 < nit) gload(kt + 32);
        f32x16 sa = {}, sb = {};
        {
            short8 kf0 = *(const short8*)&sK[l31 * 64 + (((0 + hi) ^ swl) * 8)];
            short8 kf1 = *(const short8*)&sK[l31 * 64 + (((2 + hi) ^ swl) * 8)];
            short8 kf2 = *(const short8*)&sK[l31 * 64 + (((4 + hi) ^ swl) * 8)];
            short8 kf3 = *(const short8*)&sK[l31 * 64 + (((6 + hi) ^ swl) * 8)];
            sa = __builtin_amdgcn_mfma_f32_32x32x16_bf16(kf0, qf[0], sa, 0, 0, 0);
            sb = __builtin_amdgcn_mfma_f32_32x32x16_bf16(kf2, qf[2], sb, 0, 0, 0);
            sa = __builtin_amdgcn_mfma_f32_32x32x16_bf16(kf1, qf[1], sa, 0, 0, 0);
            sb = __builtin_amdgcn_mfma_f32_32x32x16_bf16(kf3, qf[3], sb, 0, 0, 0);
        }
        float raw[16];
        #pragma unroll
        for (int r = 0; r < 16; r++) raw[r] = sa[r] + sb[r];
        if (it == nit - 1) {
            #pragma unroll
            for (int r = 0; r < 16; r++) {
                int crow = (r & 3) + 8 * (r >> 2) + 4 * hi;
                raw[r] = (crow <= l31) ? raw[r] : -1e30f;
            }
        }
        float t8[8];
        #pragma unroll
        for (int i = 0; i < 8; i++) t8[i] = fmaxf(raw[i], raw[i + 8]);
        float t4a = fmaxf(t8[0], t8[1]), t4b = fmaxf(t8[2], t8[3]);
        float t4c = fmaxf(t8[4], t8[5]), t4d = fmaxf(t8[6], t8[7]);
        float tm = fmaxf(fmaxf(t4a, t4b), fmaxf(t4c, t4d));
        tm = fmaxf(tm, __shfl_xor(tm, 32));
        float stm = tm * SC;
        if (!__all(stm - mrun <= 8.0f)) {       // defer-max (T13, THR=8)
            float mn = fmaxf(mrun, stm);
            float scale = exp2f(mrun - mn);
            lsum *= scale;
            #pragma unroll
            for (int r = 0; r < 16; r++) { o0[r] *= scale; o1[r] *= scale; }
            mrun = mn;
        }
        float ps[16];
        float rs = 0.f;
        #pragma unroll
        for (int r = 0; r < 16; r++) {
            ps[r] = exp2f(fmaf(raw[r], SC, -mrun));
            rs += ps[r];
        }
        rs += __shfl_xor(rs, 32);
        lsum += rs;
        u32 c[8], sw[8];
        #pragma unroll
        for (int i = 0; i < 8; i++) c[i] = pk2(ps[2 * i], ps[2 * i + 1]);
        #pragma unroll
        for (int i = 0; i < 8; i++) sw[i] = (u32)__shfl_xor((int)c[i], 32);
        union { u32 u[4]; short8 s8; } pb0, pb1;
        pb0.u[0] = hi ? sw[2] : c[0];
        pb0.u[1] = hi ? sw[3] : c[1];
        pb0.u[2] = hi ? c[2]  : sw[0];
        pb0.u[3] = hi ? c[3]  : sw[1];
        pb1.u[0] = hi ? sw[6] : c[4];
        pb1.u[1] = hi ? sw[7] : c[5];
        pb1.u[2] = hi ? c[6]  : sw[4];
        pb1.u[3] = hi ? c[7]  : sw[5];
        #pragma unroll
        for (int kh = 0; kh < 2; kh++) {
            const short8* pbp = kh ? &pb1.s8 : &pb0.s8;
            int p = (((kh * 2 + hi) ^ swv) * 8);
            short8 vf0 = *(const short8*)&sV[l31 * 32 + p];
            short8 vf1 = *(const short8*)&sV[(32 + l31) * 32 + p];
            o0 = __builtin_amdgcn_mfma_f32_32x32x16_bf16(vf0, *pbp, o0, 0, 0, 0);
            o1 = __builtin_amdgcn_mfma_f32_32x32x16_bf16(vf1, *pbp, o1, 0, 0, 0);
        }
        if (it + 1 < nit) swrite();
    }

    float inv = 1.0f / lsum;
    int t = q0 + l31;
    size_t base = ((size_t)(b * 1024 + t)) * 768 + h * 64;
    #pragma unroll
    for (int rq = 0; rq < 4; rq++) {
        ushort4 u0, u1;
        u0.x = f2bf(o0[4 * rq + 0] * inv); u0.y = f2bf(o0[4 * rq + 1] * inv);
        u0.z = f2bf(o0[4 * rq + 2] * inv); u0.w = f2bf(o0[4 * rq + 3] * inv);
        u1.x = f2bf(o1[4 * rq + 0] * inv); u1.y = f2bf(o1[4 * rq + 1] * inv);
        u1.z = f2bf(o1[4 * rq + 2] * inv); u1.w = f2bf(o1[4 * rq + 3] * inv);
        *(ushort4*)&O[base + rq * 8 + hi * 4]      = u0;
        *(ushort4*)&O[base + 32 + rq * 8 + hi * 4] = u1;
    }
}

extern "C" void kernel_launch(void* const* d_in, const int* in_sizes, int n_in,
                              void* d_out, int out_size, void* d_ws, size_t ws_size,
                              hipStream_t stream)
{
    const float* x     = (const float*)d_in[0];
    const float* W_qkv = (const float*)d_in[1];
    const float* b_qkv = (const float*)d_in[2];
    const float* W_out = (const float*)d_in[3];
    const float* b_out = (const float*)d_in[4];
    float* out = (float*)d_out;

    char* w = (char*)d_ws;
    u16* xb   = (u16*)w; w += (size_t)8192 * 768 * 2;
    u16* wqt  = (u16*)w; w += (size_t)2304 * 768 * 2;
    u16* wot  = (u16*)w; w += (size_t)768 * 768 * 2;
    u16* qkv  = (u16*)w; w += (size_t)8192 * 2304 * 2;
    u16* vt   = (u16*)w; w += (size_t)96 * 64 * 1024 * 2;
    u16* ao   = (u16*)w; w += (size_t)8192 * 768 * 2;

    k_prep<<<dim3(8448), 256, 0, stream>>>(x, xb, W_qkv, wqt, W_out, wot);
    k_gemm_bt<2><<<dim3(64, 18), 256, 0, stream>>>(xb, wqt, b_qkv, nullptr, qkv, 8192, 2304, 768);
    k_vt<<<dim3(16, 96), 256, 0, stream>>>(qkv, vt);
    k_attn<<<dim3(3072), 64, 0, stream>>>(qkv, vt, ao);
    k_gemm_bt<0><<<dim3(64, 6), 256, 0, stream>>>(ao, wot, b_out, out, nullptr, 8192, 768, 768);
}